// Round 1
// baseline (671.601 us; speedup 1.0000x reference)
//
#include <hip/hip_runtime.h>

typedef _Float16 half8 __attribute__((ext_vector_type(8)));
typedef _Float16 half4v __attribute__((ext_vector_type(4)));
typedef float f32x4 __attribute__((ext_vector_type(4)));

// Shapes fixed by the problem: B=2,H=16,N=2048,D=64
__global__ __launch_bounds__(256, 2)
void attn_fused(const float* __restrict__ qg_, const float* __restrict__ kg_,
                const float* __restrict__ vg_, const int* __restrict__ mg_,
                float* __restrict__ outg_, float* __restrict__ attng_)
{
    constexpr int N = 2048, D = 64, TM = 128, BK = 128, NCH = 16;
    constexpr int QS = 72, KS = 72, VTS = 136, PS = 72;   // LDS strides in halves (+8 pad)
    constexpr float INVN = 1.0f / 2048.0f;

    __shared__ _Float16 Qs[TM * QS];        // 18432 B
    __shared__ _Float16 Ksh[BK * KS];       // 18432 B
    __shared__ _Float16 Vts[D * VTS];       // 17408 B, transposed: [d][key]
    __shared__ _Float16 Ps[TM * PS];        // 18432 B, per-wave-private row slices
    __shared__ unsigned char cm[N];         // 2048 B: 1 = keep, 0 = masked col
    // total ~74.8 KB -> 2 workgroups/CU

    const int tid  = threadIdx.x;
    const int wid  = tid >> 6;
    const int lane = tid & 63;
    const int quad = lane >> 4;
    const int l15  = lane & 15;

    const int bh = blockIdx.x & 31;   // same bh -> same XCD (L2 locality for K/V)
    const int qt = blockIdx.x >> 5;
    const int b  = bh >> 4;

    const float* qg = qg_ + ((size_t)bh * N + qt * TM) * D;
    const float* kg = kg_ + (size_t)bh * N * D;
    const float* vg = vg_ + (size_t)bh * N * D;
    const int*   mg = mg_ + (size_t)b * N;
    float* attng = attng_ + ((size_t)bh * N + (size_t)qt * TM) * N;
    float* outg  = outg_  + ((size_t)bh * N + qt * TM) * D;

    // ---- stage Q (x 1/8, fp16) and column-mask flags ----
#pragma unroll
    for (int i = 0; i < 8; ++i) {
        int f = tid + 256 * i;
        int row = f >> 4, d = (f & 15) * 4;
        float4 x = *reinterpret_cast<const float4*>(qg + (size_t)row * D + d);
        half4v hv;
        hv[0] = (_Float16)(x.x * 0.125f);
        hv[1] = (_Float16)(x.y * 0.125f);
        hv[2] = (_Float16)(x.z * 0.125f);
        hv[3] = (_Float16)(x.w * 0.125f);
        *reinterpret_cast<half4v*>(&Qs[row * QS + d]) = hv;
        cm[f] = (unsigned char)(mg[f] ? 0 : 1);
    }

    // per-lane row-mask flags for the rows this lane's C-frags own
    float rowm[2][4];
#pragma unroll
    for (int mb = 0; mb < 2; ++mb)
#pragma unroll
        for (int r = 0; r < 4; ++r) {
            int row = qt * TM + wid * 32 + mb * 16 + quad * 4 + r;
            rowm[mb][r] = (float)mg[row];
        }

    __syncthreads();

    // Q A-frags live in registers for the whole kernel
    half8 qf[2][2];
#pragma unroll
    for (int mb = 0; mb < 2; ++mb)
#pragma unroll
        for (int ks = 0; ks < 2; ++ks)
            qf[mb][ks] = *reinterpret_cast<half8*>(
                &Qs[(wid * 32 + mb * 16 + l15) * QS + ks * 32 + quad * 8]);

    float lsum[2][4] = {{0,0,0,0},{0,0,0,0}};

    // ================= PASS 1: row sums of exp(s) =================
    for (int kc = 0; kc < NCH; ++kc) {
        __syncthreads();
#pragma unroll
        for (int i = 0; i < 8; ++i) {
            int f = tid + 256 * i;
            int row = f >> 4, d = (f & 15) * 4;
            float4 x = *reinterpret_cast<const float4*>(kg + (size_t)(kc * BK + row) * D + d);
            half4v hv;
            hv[0] = (_Float16)x.x; hv[1] = (_Float16)x.y;
            hv[2] = (_Float16)x.z; hv[3] = (_Float16)x.w;
            *reinterpret_cast<half4v*>(&Ksh[row * KS + d]) = hv;
        }
        __syncthreads();

#pragma unroll
        for (int mb = 0; mb < 2; ++mb) {
#pragma unroll
            for (int nb = 0; nb < 8; ++nb) {
                f32x4 acc = {0.f, 0.f, 0.f, 0.f};
#pragma unroll
                for (int ks = 0; ks < 2; ++ks) {
                    half8 bf = *reinterpret_cast<half8*>(
                        &Ksh[(nb * 16 + l15) * KS + ks * 32 + quad * 8]);
                    acc = __builtin_amdgcn_mfma_f32_16x16x32_f16(qf[mb][ks], bf, acc, 0, 0, 0);
                }
                float cmf = (float)cm[kc * BK + nb * 16 + l15];
#pragma unroll
                for (int r = 0; r < 4; ++r)
                    lsum[mb][r] += cmf * __expf(acc[r]);
            }
        }
    }

    // reduce over the 16 lanes (columns) of each quad group
#pragma unroll
    for (int mb = 0; mb < 2; ++mb)
#pragma unroll
        for (int r = 0; r < 4; ++r) {
            float s = lsum[mb][r];
            s += __shfl_xor(s, 1, 64);
            s += __shfl_xor(s, 2, 64);
            s += __shfl_xor(s, 4, 64);
            s += __shfl_xor(s, 8, 64);
            lsum[mb][r] = s;
        }

    float rscale[2][4], radd[2][4];
#pragma unroll
    for (int mb = 0; mb < 2; ++mb)
#pragma unroll
        for (int r = 0; r < 4; ++r) {
            bool uni = (rowm[mb][r] != 0.0f) || !(lsum[mb][r] > 0.0f);
            rscale[mb][r] = uni ? 0.0f : 1.0f / lsum[mb][r];
            radd[mb][r]   = uni ? INVN : 0.0f;
        }

    f32x4 Oacc[2][4];
#pragma unroll
    for (int mb = 0; mb < 2; ++mb)
#pragma unroll
        for (int nd = 0; nd < 4; ++nd)
            Oacc[mb][nd] = (f32x4){0.f, 0.f, 0.f, 0.f};

    // ========= PASS 2: recompute S, write P, accumulate O = P.V =========
    for (int kc = 0; kc < NCH; ++kc) {
        __syncthreads();
#pragma unroll
        for (int i = 0; i < 8; ++i) {
            int f = tid + 256 * i;
            int row = f >> 4, d = (f & 15) * 4;
            float4 x = *reinterpret_cast<const float4*>(kg + (size_t)(kc * BK + row) * D + d);
            half4v hv;
            hv[0] = (_Float16)x.x; hv[1] = (_Float16)x.y;
            hv[2] = (_Float16)x.z; hv[3] = (_Float16)x.w;
            *reinterpret_cast<half4v*>(&Ksh[row * KS + d]) = hv;
        }
        // V chunk, transposed in registers -> Vts[d][key], b128 conflict-free writes
#pragma unroll
        for (int rr = 0; rr < 4; ++rr) {
            int key0 = rr * 32 + wid * 8;
            half8 hh;
#pragma unroll
            for (int j = 0; j < 8; ++j)
                hh[j] = (_Float16)vg[(size_t)(kc * BK + key0 + j) * D + lane];
            *reinterpret_cast<half8*>(&Vts[lane * VTS + key0]) = hh;
        }
        __syncthreads();

        f32x4 S[2][8];
#pragma unroll
        for (int mb = 0; mb < 2; ++mb)
#pragma unroll
            for (int nb = 0; nb < 8; ++nb) {
                f32x4 acc = {0.f, 0.f, 0.f, 0.f};
#pragma unroll
                for (int ks = 0; ks < 2; ++ks) {
                    half8 bf = *reinterpret_cast<half8*>(
                        &Ksh[(nb * 16 + l15) * KS + ks * 32 + quad * 8]);
                    acc = __builtin_amdgcn_mfma_f32_16x16x32_f16(qf[mb][ks], bf, acc, 0, 0, 0);
                }
                S[mb][nb] = acc;
            }

#pragma unroll
        for (int h = 0; h < 2; ++h) {
#pragma unroll
            for (int nb2 = 0; nb2 < 4; ++nb2) {
                int nb = h * 4 + nb2;
                int col = kc * BK + nb * 16 + l15;
                float cmf = (float)cm[col];
#pragma unroll
                for (int mb = 0; mb < 2; ++mb) {
#pragma unroll
                    for (int r = 0; r < 4; ++r) {
                        float p = cmf * __expf(S[mb][nb][r]) * rscale[mb][r] + radd[mb][r];
                        attng[(size_t)(wid * 32 + mb * 16 + quad * 4 + r) * N + col] = p;
                        Ps[(wid * 32 + mb * 16 + quad * 4 + r) * PS + nb2 * 16 + l15] = (_Float16)p;
                    }
                }
            }
            // Ps is wave-private (rows owned by this wave); only need LDS drain, not a barrier
            asm volatile("s_waitcnt lgkmcnt(0)" ::: "memory");
#pragma unroll
            for (int ks = 0; ks < 2; ++ks) {
                half8 af[2];
#pragma unroll
                for (int mb = 0; mb < 2; ++mb)
                    af[mb] = *reinterpret_cast<half8*>(
                        &Ps[(wid * 32 + mb * 16 + l15) * PS + ks * 32 + quad * 8]);
#pragma unroll
                for (int nd = 0; nd < 4; ++nd) {
                    half8 bf = *reinterpret_cast<half8*>(
                        &Vts[(nd * 16 + l15) * VTS + h * 64 + ks * 32 + quad * 8]);
#pragma unroll
                    for (int mb = 0; mb < 2; ++mb)
                        Oacc[mb][nd] = __builtin_amdgcn_mfma_f32_16x16x32_f16(af[mb], bf, Oacc[mb][nd], 0, 0, 0);
                }
            }
        }
    }

    // ---- store O ----
#pragma unroll
    for (int mb = 0; mb < 2; ++mb)
#pragma unroll
        for (int nd = 0; nd < 4; ++nd)
#pragma unroll
            for (int r = 0; r < 4; ++r)
                outg[(size_t)(wid * 32 + mb * 16 + quad * 4 + r) * D + nd * 16 + l15] =
                    Oacc[mb][nd][r];
}

extern "C" void kernel_launch(void* const* d_in, const int* in_sizes, int n_in,
                              void* d_out, int out_size, void* d_ws, size_t ws_size,
                              hipStream_t stream) {
    const float* q   = (const float*)d_in[0];
    const float* k   = (const float*)d_in[1];
    const float* v   = (const float*)d_in[2];
    const int*   msk = (const int*)d_in[3];
    float* out  = (float*)d_out;
    float* attn = out + (size_t)2 * 16 * 2048 * 64;   // output first, then attn
    dim3 grid(512), block(256);
    hipLaunchKernelGGL(attn_fused, grid, block, 0, stream, q, k, v, msk, out, attn);
}

// Round 3
// 650.154 us; speedup vs baseline: 1.0330x; 1.0330x over previous
//
#include <hip/hip_runtime.h>

typedef _Float16 half8 __attribute__((ext_vector_type(8)));
typedef _Float16 half4v __attribute__((ext_vector_type(4)));
typedef float f32x4 __attribute__((ext_vector_type(4)));

#if __has_builtin(__builtin_amdgcn_exp2f)
#define EXP2F(x) __builtin_amdgcn_exp2f(x)
#else
#define EXP2F(x) exp2f(x)
#endif

// Shapes fixed by the problem: B=2,H=16,N=2048,D=64
__global__ __launch_bounds__(256, 2)
void attn_fused(const float* __restrict__ qg_, const float* __restrict__ kg_,
                const float* __restrict__ vg_, const int* __restrict__ mg_,
                float* __restrict__ outg_, float* __restrict__ attng_)
{
    constexpr int N = 2048, D = 64, TM = 128, BK = 128, NCH = 16;
    constexpr int QS = 72, KS = 72, VTS = 136, PS = 72;   // LDS strides in halves (+8 pad)
    constexpr float INVN = 1.0f / 2048.0f;
    // fold 1/TEMPERATURE and log2(e) into Q so scores are exp2-ready
    constexpr float QSCALE = 1.44269504088896340736f * 0.125f;

    __shared__ _Float16 Qs[TM * QS];        // 18432 B
    __shared__ _Float16 Ksh[BK * KS];       // 18432 B
    __shared__ _Float16 Vts[D * VTS];       // 17408 B, transposed: [d][key]
    __shared__ _Float16 Ps[TM * PS];        // 18432 B, per-wave-private row slices
    __shared__ unsigned char cm[N];         // 2048 B: 1 = keep, 0 = masked col
    // total ~74.8 KB -> 2 workgroups/CU (LDS-bound; VGPRs are not the limiter)

    const int tid  = threadIdx.x;
    const int wid  = tid >> 6;
    const int lane = tid & 63;
    const int quad = lane >> 4;
    const int l15  = lane & 15;

    const int bh = blockIdx.x & 31;   // same bh -> same XCD (L2 locality for K/V)
    const int qt = blockIdx.x >> 5;
    const int b  = bh >> 4;

    const float* qg = qg_ + ((size_t)bh * N + qt * TM) * D;
    const float* kg = kg_ + (size_t)bh * N * D;
    const float* vg = vg_ + (size_t)bh * N * D;
    const int*   mg = mg_ + (size_t)b * N;
    float* attng = attng_ + ((size_t)bh * N + (size_t)qt * TM) * N;
    float* outg  = outg_  + ((size_t)bh * N + qt * TM) * D;

    // ---- stage Q (x log2e/8, fp16) and column-mask flags ----
#pragma unroll
    for (int i = 0; i < 8; ++i) {
        int f = tid + 256 * i;
        int row = f >> 4, d = (f & 15) * 4;
        float4 x = *reinterpret_cast<const float4*>(qg + (size_t)row * D + d);
        half4v hv;
        hv[0] = (_Float16)(x.x * QSCALE);
        hv[1] = (_Float16)(x.y * QSCALE);
        hv[2] = (_Float16)(x.z * QSCALE);
        hv[3] = (_Float16)(x.w * QSCALE);
        *reinterpret_cast<half4v*>(&Qs[row * QS + d]) = hv;
        cm[f] = (unsigned char)(mg[f] ? 0 : 1);
    }

    // per-lane row-mask flags for the rows this lane's C-frags own
    float rowm[2][4];
#pragma unroll
    for (int mb = 0; mb < 2; ++mb)
#pragma unroll
        for (int r = 0; r < 4; ++r) {
            int row = qt * TM + wid * 32 + mb * 16 + quad * 4 + r;
            rowm[mb][r] = (float)mg[row];
        }

    __syncthreads();

    // Q A-frags live in registers for the whole kernel
    half8 qf[2][2];
#pragma unroll
    for (int mb = 0; mb < 2; ++mb)
#pragma unroll
        for (int ks = 0; ks < 2; ++ks)
            qf[mb][ks] = *reinterpret_cast<half8*>(
                &Qs[(wid * 32 + mb * 16 + l15) * QS + ks * 32 + quad * 8]);

    float lsum[2][4] = {{0,0,0,0},{0,0,0,0}};

    // ================= PASS 1: row sums of exp2(s) =================
    for (int kc = 0; kc < NCH; ++kc) {
        __syncthreads();
#pragma unroll
        for (int i = 0; i < 8; ++i) {
            int f = tid + 256 * i;
            int row = f >> 4, d = (f & 15) * 4;
            float4 x = *reinterpret_cast<const float4*>(kg + (size_t)(kc * BK + row) * D + d);
            half4v hv;
            hv[0] = (_Float16)x.x; hv[1] = (_Float16)x.y;
            hv[2] = (_Float16)x.z; hv[3] = (_Float16)x.w;
            *reinterpret_cast<half4v*>(&Ksh[row * KS + d]) = hv;
        }
        __syncthreads();

#pragma unroll
        for (int mb = 0; mb < 2; ++mb) {
#pragma unroll
            for (int nb = 0; nb < 8; ++nb) {
                f32x4 acc = {0.f, 0.f, 0.f, 0.f};
#pragma unroll
                for (int ks = 0; ks < 2; ++ks) {
                    half8 bf = *reinterpret_cast<half8*>(
                        &Ksh[(nb * 16 + l15) * KS + ks * 32 + quad * 8]);
                    acc = __builtin_amdgcn_mfma_f32_16x16x32_f16(qf[mb][ks], bf, acc, 0, 0, 0);
                }
                float cmf = (float)cm[kc * BK + nb * 16 + l15];
#pragma unroll
                for (int r = 0; r < 4; ++r)
                    lsum[mb][r] += cmf * EXP2F(acc[r]);
            }
        }
    }

    // reduce over the 16 lanes (columns) of each quad group
#pragma unroll
    for (int mb = 0; mb < 2; ++mb)
#pragma unroll
        for (int r = 0; r < 4; ++r) {
            float s = lsum[mb][r];
            s += __shfl_xor(s, 1, 64);
            s += __shfl_xor(s, 2, 64);
            s += __shfl_xor(s, 4, 64);
            s += __shfl_xor(s, 8, 64);
            lsum[mb][r] = s;
        }

    float rscale[2][4], radd[2][4];
#pragma unroll
    for (int mb = 0; mb < 2; ++mb)
#pragma unroll
        for (int r = 0; r < 4; ++r) {
            bool uni = (rowm[mb][r] != 0.0f) || !(lsum[mb][r] > 0.0f);
            rscale[mb][r] = uni ? 0.0f : 1.0f / lsum[mb][r];
            radd[mb][r]   = uni ? INVN : 0.0f;
        }

    f32x4 Oacc[2][4];
#pragma unroll
    for (int mb = 0; mb < 2; ++mb)
#pragma unroll
        for (int nd = 0; nd < 4; ++nd)
            Oacc[mb][nd] = (f32x4){0.f, 0.f, 0.f, 0.f};

    // ========= PASS 2: recompute S, write P (LDS+global), accumulate O = P.V =========
    for (int kc = 0; kc < NCH; ++kc) {
        __syncthreads();
#pragma unroll
        for (int i = 0; i < 8; ++i) {
            int f = tid + 256 * i;
            int row = f >> 4, d = (f & 15) * 4;
            float4 x = *reinterpret_cast<const float4*>(kg + (size_t)(kc * BK + row) * D + d);
            half4v hv;
            hv[0] = (_Float16)x.x; hv[1] = (_Float16)x.y;
            hv[2] = (_Float16)x.z; hv[3] = (_Float16)x.w;
            *reinterpret_cast<half4v*>(&Ksh[row * KS + d]) = hv;
        }
        // V chunk, transposed in registers -> Vts[d][key], b128 conflict-free writes
#pragma unroll
        for (int rr = 0; rr < 4; ++rr) {
            int key0 = rr * 32 + wid * 8;
            half8 hh;
#pragma unroll
            for (int j = 0; j < 8; ++j)
                hh[j] = (_Float16)vg[(size_t)(kc * BK + key0 + j) * D + lane];
            *reinterpret_cast<half8*>(&Vts[lane * VTS + key0]) = hh;
        }
        __syncthreads();

        f32x4 S[2][8];
#pragma unroll
        for (int mb = 0; mb < 2; ++mb)
#pragma unroll
            for (int nb = 0; nb < 8; ++nb) {
                f32x4 acc = {0.f, 0.f, 0.f, 0.f};
#pragma unroll
                for (int ks = 0; ks < 2; ++ks) {
                    half8 bf = *reinterpret_cast<half8*>(
                        &Ksh[(nb * 16 + l15) * KS + ks * 32 + quad * 8]);
                    acc = __builtin_amdgcn_mfma_f32_16x16x32_f16(qf[mb][ks], bf, acc, 0, 0, 0);
                }
                S[mb][nb] = acc;
            }

#pragma unroll
        for (int h = 0; h < 2; ++h) {
            // ---- P -> LDS (fp16), per-wave-private rows ----
#pragma unroll
            for (int nb2 = 0; nb2 < 4; ++nb2) {
                int nb = h * 4 + nb2;
                float cmf = (float)cm[kc * BK + nb * 16 + l15];
#pragma unroll
                for (int mb = 0; mb < 2; ++mb) {
#pragma unroll
                    for (int r = 0; r < 4; ++r) {
                        float p = cmf * EXP2F(S[mb][nb][r]) * rscale[mb][r] + radd[mb][r];
                        Ps[(wid * 32 + mb * 16 + quad * 4 + r) * PS + nb2 * 16 + l15] = (_Float16)p;
                    }
                }
            }
            // Ps rows are wave-private; LDS pipe is in-order per wave -> drain, no barrier
            asm volatile("s_waitcnt lgkmcnt(0)" ::: "memory");

            // ---- attn tile: vectorized readback + nontemporal dwordx4 stores ----
            // issue stores BEFORE the PV MFMAs so they drain under compute
#pragma unroll
            for (int r8 = 0; r8 < 8; ++r8) {
                int rl = r8 * 4 + quad;                       // 0..31, wave-local row
                half4v ph = *reinterpret_cast<half4v*>(
                    &Ps[(wid * 32 + rl) * PS + l15 * 4]);
                f32x4 pf;
                pf[0] = (float)ph[0]; pf[1] = (float)ph[1];
                pf[2] = (float)ph[2]; pf[3] = (float)ph[3];
                float* dst = attng + (size_t)(wid * 32 + rl) * N + kc * BK + h * 64 + l15 * 4;
                __builtin_nontemporal_store(pf, reinterpret_cast<f32x4*>(dst));
            }

            // ---- O += P.V for this 64-col half ----
#pragma unroll
            for (int ks = 0; ks < 2; ++ks) {
                half8 af[2];
#pragma unroll
                for (int mb = 0; mb < 2; ++mb)
                    af[mb] = *reinterpret_cast<half8*>(
                        &Ps[(wid * 32 + mb * 16 + l15) * PS + ks * 32 + quad * 8]);
#pragma unroll
                for (int nd = 0; nd < 4; ++nd) {
                    half8 bf = *reinterpret_cast<half8*>(
                        &Vts[(nd * 16 + l15) * VTS + h * 64 + ks * 32 + quad * 8]);
#pragma unroll
                    for (int mb = 0; mb < 2; ++mb)
                        Oacc[mb][nd] = __builtin_amdgcn_mfma_f32_16x16x32_f16(af[mb], bf, Oacc[mb][nd], 0, 0, 0);
                }
            }
        }
    }

    // ---- store O (fp32 accumulators, nontemporal) ----
#pragma unroll
    for (int mb = 0; mb < 2; ++mb)
#pragma unroll
        for (int nd = 0; nd < 4; ++nd)
#pragma unroll
            for (int r = 0; r < 4; ++r)
                __builtin_nontemporal_store(
                    Oacc[mb][nd][r],
                    outg + (size_t)(wid * 32 + mb * 16 + quad * 4 + r) * D + nd * 16 + l15);
}

extern "C" void kernel_launch(void* const* d_in, const int* in_sizes, int n_in,
                              void* d_out, int out_size, void* d_ws, size_t ws_size,
                              hipStream_t stream) {
    const float* q   = (const float*)d_in[0];
    const float* k   = (const float*)d_in[1];
    const float* v   = (const float*)d_in[2];
    const int*   msk = (const int*)d_in[3];
    float* out  = (float*)d_out;
    float* attn = out + (size_t)2 * 16 * 2048 * 64;   // output first, then attn
    dim3 grid(512), block(256);
    hipLaunchKernelGGL(attn_fused, grid, block, 0, stream, q, k, v, msk, out, attn);
}